// Round 16
// baseline (262.648 us; speedup 1.0000x reference)
//
#include <hip/hip_runtime.h>

// ---------------------------------------------------------------------------
// network_49581102465567: 5-layer MLP, codebook quantize after layer 2.
// Folds: Wa = w2@w1 [512x1024], Wc = (w5@w4)@w3 [512x512].
// Round 21: R20 base (best, 254.7us) + BK 64->32 across all GEMM bodies to
// DOUBLE blocks/CU (the one axis every win/loss this session correlated
// with): gemmQ/gemmout LDS 49->25.6KB -> 6 blk/CU (24 waves at the vmcnt
// stall); folds 32->16KB; foldA tile aliased on smem -> 6 blk/CU for casts.
// Bit-identical numerics: same ascending k=0,32,64.. MFMA list per acc
// (BK=64 did two per barrier-pair), same CH chunk boundaries, same RNE.
// Sync skeleton = proven counted-vmcnt + lgkmcnt(0); LPS: 3 (BM=128),
// 2 (folds). Staging swizzle re-derived for 64B rows:
//   write: lane(srow=lane>>2, c=lane&3) sources global chunk c^(srow&3)
//   read:  cch = (quad ^ (l15&3))*8   (same involution; <=4-way, off-path)
// Dispatches: prepw -> foldA{fold1,fold2,ba,w3T,xcast} -> foldB{fold3,bc,
// gemmQ} -> gemmout. absmax must stay 0.005981445.
// ---------------------------------------------------------------------------

typedef __bf16 v8bf __attribute__((ext_vector_type(8)));
typedef float  v4f  __attribute__((ext_vector_type(4)));

#define Bdim   16384
#define DIN    1024
#define DOUT   512
#define H1dim  4096
#define H3dim  2048
#define H4dim  2048

#define GLOBAL_AS __attribute__((address_space(1)))
#define LDS_AS    __attribute__((address_space(3)))

__device__ __forceinline__ void load16_to_lds(const __bf16* g, __bf16* l) {
  __builtin_amdgcn_global_load_lds((const GLOBAL_AS unsigned int*)g,
                                   (LDS_AS unsigned int*)l, 16, 0, 0);
}

__device__ __forceinline__ unsigned pack2bf(float a, float b) {
  return (unsigned)__builtin_bit_cast(unsigned short, (__bf16)a) |
         ((unsigned)__builtin_bit_cast(unsigned short, (__bf16)b) << 16);
}

// ---- transposes (64 in-rows x 32 in-cols -> 128B writes) ----
__device__ __forceinline__ void transpose_body(const float* __restrict__ in,
                                               __bf16* __restrict__ out,
                                               int R, int C, int bx, int by,
                                               float (*tile)[68]) {
  const int c0 = bx * 32, r0 = by * 64;
  const int t = threadIdx.x, tr = t >> 5, tc = t & 31;
#pragma unroll
  for (int i = 0; i < 8; ++i)
    tile[tc][tr + i * 8] = in[(size_t)(r0 + tr + i * 8) * C + (c0 + tc)];
  __syncthreads();
  const int orow = t >> 3, oc = (t & 7) * 8;
  float4 a = *(const float4*)&tile[orow][oc];
  float4 b = *(const float4*)&tile[orow][oc + 4];
  int4 o;
  o.x = pack2bf(a.x, a.y); o.y = pack2bf(a.z, a.w);
  o.z = pack2bf(b.x, b.y); o.w = pack2bf(b.z, b.w);
  *(int4*)&out[(size_t)(c0 + orow) * R + (r0 + oc)] = o;
}

// ---- coalesced cast: block covers 4096 elems; chunk c, thread t ----
__device__ __forceinline__ void cast16_body(const float* __restrict__ in,
                                            __bf16* __restrict__ out, int b) {
  const int t = threadIdx.x;
  const size_t base = (size_t)b * 4096;
#pragma unroll
  for (int c = 0; c < 4; ++c) {
    const size_t i = base + c * 1024 + t * 4;
    float4 v = *(const float4*)&in[i];
    uint2 o;
    o.x = pack2bf(v.x, v.y);
    o.y = pack2bf(v.z, v.w);
    *(uint2*)&out[i] = o;
  }
}

// ---- dispatch 1: w1/w4 transposes + w2/w5 casts (4864 blocks) ----
__global__ void prepw_kernel(const float* __restrict__ w1, __bf16* __restrict__ w1T,
                             const float* __restrict__ w4, __bf16* __restrict__ w4T,
                             const float* __restrict__ w2, __bf16* __restrict__ w2b,
                             const float* __restrict__ w5, __bf16* __restrict__ w5b) {
  __shared__ float tile[32][68];
  int b = blockIdx.x;
  if (b < 2048) {                 // w1 [4096][1024] -> w1T
    transpose_body(w1, w1T, H1dim, DIN, b & 31, b >> 5, tile);
  } else if (b < 4096) {          // w4 -> w4T
    b -= 2048;
    transpose_body(w4, w4T, H4dim, H3dim, b & 63, b >> 6, tile);
  } else if (b < 4608) {          // w2 -> bf16
    cast16_body(w2, w2b, b - 4096);
  } else {                        // w5 -> bf16
    cast16_body(w5, w5b, b - 4608);
  }
}

// ---- folded bias bodies (R11/R16) ----
__device__ __forceinline__ void bias_ba_body(int bb, const float* __restrict__ b1,
                                             const float* __restrict__ w2,
                                             const float* __restrict__ b2,
                                             float* __restrict__ ba) {
  const int wave = threadIdx.x >> 6, lane = threadIdx.x & 63;
  const int j = bb * 4 + wave;
  float s = 0.f;
  for (int k = lane; k < H1dim; k += 64) s += b1[k] * w2[(size_t)j * H1dim + k];
#pragma unroll
  for (int off = 32; off; off >>= 1) s += __shfl_xor(s, off, 64);
  if (lane == 0) ba[j] = s + b2[j];
}

__device__ __forceinline__ void bias_bc_body(int bb, const float* __restrict__ b3,
                                             const __bf16* __restrict__ WtT,
                                             const float* __restrict__ b4,
                                             const float* __restrict__ w5,
                                             const float* __restrict__ b5,
                                             float* __restrict__ bc) {
  const int wave = threadIdx.x >> 6, lane = threadIdx.x & 63;
  const int j = bb * 4 + wave;
  float s = 0.f;
  for (int k = lane; k < H4dim; k += 64)
    s += b3[k] * (float)WtT[(size_t)j * H4dim + k] + b4[k] * w5[(size_t)j * H4dim + k];
#pragma unroll
  for (int off = 32; off; off >>= 1) s += __shfl_xor(s, off, 64);
  if (lane == 0) bc[j] = s + b5[j];
}

// ---- unified bf16 GEMM body: BMx64 tile, BK=32, counted-vmcnt ----
// MODE_W: chunk-grouped fold (CH), bf16 out. MODE_Q: +bias, quantize,
// bf16 out. MODE_OUT: +bias, fp32 out.
// LDS per buf: A = BM*32, B = 64*32 elems (rows of 64B).
// Staging: 1 gload = 16 rows x 64B; lane -> (srow=lane>>2, chunk=lane&3),
// source col pre-swizzled: ((lane&3)^(srow&3))*8; LDS dest linear.
// Read: row (.. + l15), slot (quad ^ (l15&3))*8 — matching involution.
// MFMA sequence per acc: k = 0,32,64,... ascending — identical to BK=64.
enum { MODE_W = 0, MODE_Q = 1, MODE_OUT = 2 };

#define ASM_BAR() asm volatile("s_barrier" ::: "memory")

template <int MODE, int BM>
__device__ __forceinline__ void gemm_body(__bf16* As, __bf16* Bs, float* cbs,
                                          int bx, int by,
                                          const __bf16* __restrict__ A,
                                          const __bf16* __restrict__ Bt,
                                          void* __restrict__ Cout,
                                          const float* __restrict__ bias,
                                          const float* __restrict__ codebook,
                                          int M, int N, int K, int CH) {
  const int t = threadIdx.x;
  const int m0 = bx * BM, n0 = by * 64;
  if constexpr (MODE == MODE_Q) cbs[t] = codebook[t];

  const int lane = t & 63, wave = t >> 6;
  const int quad = lane >> 4, l15 = lane & 15;
  constexpr int MI = BM / 32;                 // A fragments per wave
  constexpr int AP = BM / 64;                 // A gloads per wave (16 rows ea)
  const int wm = (wave & 1) * (BM / 2), wn = (wave >> 1) * 32;

  // staging coords (64B rows)
  const int srow = lane >> 2;
  const int scol = (((lane & 3) ^ (srow & 3)) * 8);   // pre-swizzled source
  const __bf16* gA = A  + (size_t)(m0 + (BM / 4) * wave + srow) * K + scol;
  const __bf16* gB = Bt + (size_t)(n0 + 16 * wave + srow) * K + scol;

  v4f acc[MI][2], accT[MI][2];
#pragma unroll
  for (int i = 0; i < MI; ++i)
#pragma unroll
    for (int j = 0; j < 2; ++j) {
      acc[i][j] = (v4f){0.f, 0.f, 0.f, 0.f};
      if constexpr (MODE == MODE_W) accT[i][j] = (v4f){0.f, 0.f, 0.f, 0.f};
    }

  // stage = AP + 1 gloads per wave (LPS)
  auto stage = [&](int k0, int buf) {
    __bf16* lA = As + buf * (BM * 32) + (BM / 4) * wave * 32;
    __bf16* lB = Bs + buf * (64 * 32) + 16 * wave * 32;
#pragma unroll
    for (int p = 0; p < AP; ++p)
      load16_to_lds(gA + (size_t)(16 * p) * K + k0, lA + p * 512);
    load16_to_lds(gB + k0, lB);
  };

  const int nk = K >> 5;
  const int chsteps = CH >> 5;
  stage(0, 0);
  stage(32, 1);                    // 2*LPS loads in flight

  int cc = 0;
  for (int tk = 0; tk < nk; ++tk) {
    // drain ONLY stage(tk); stage(tk+1)'s LPS loads stay in flight
    if (tk + 1 < nk) {
      if constexpr (BM == 128) asm volatile("s_waitcnt vmcnt(3)" ::: "memory");
      else                     asm volatile("s_waitcnt vmcnt(2)" ::: "memory");
    } else {
      asm volatile("s_waitcnt vmcnt(0)" ::: "memory");
    }
    ASM_BAR();                     // all waves' stage(tk) visible

    const __bf16* cA = As + (tk & 1) * (BM * 32);
    const __bf16* cB = Bs + (tk & 1) * (64 * 32);
    const int cch = (quad ^ (l15 & 3)) * 8;
    v8bf af[MI], bv[2];
#pragma unroll
    for (int i = 0; i < MI; ++i)
      af[i] = *(const v8bf*)&cA[(wm + i * 16 + l15) * 32 + cch];
#pragma unroll
    for (int j = 0; j < 2; ++j)
      bv[j] = *(const v8bf*)&cB[(wn + j * 16 + l15) * 32 + cch];
#pragma unroll
    for (int i = 0; i < MI; ++i)
#pragma unroll
      for (int j = 0; j < 2; ++j)
        acc[i][j] = __builtin_amdgcn_mfma_f32_16x16x32_bf16(af[i], bv[j], acc[i][j], 0, 0, 0);

    if constexpr (MODE == MODE_W) {
      if (++cc == chsteps) {        // chunk boundary: accT += chunk (left fold)
        cc = 0;
#pragma unroll
        for (int i = 0; i < MI; ++i)
#pragma unroll
          for (int j = 0; j < 2; ++j) {
            accT[i][j] += acc[i][j];
            acc[i][j] = (v4f){0.f, 0.f, 0.f, 0.f};
          }
      }
    }
    // Race fix (R10): fragment ds_reads must complete before any wave may
    // overwrite buf[tk&1] with stage(tk+2) DMA after the barrier.
    asm volatile("s_waitcnt lgkmcnt(0)" ::: "memory");
    ASM_BAR();                     // all waves done reading buf[tk&1]
    if (tk + 2 < nk) stage((tk + 2) << 5, tk & 1);   // refill freed buffer
  }

#pragma unroll
  for (int j = 0; j < 2; ++j) {
    const int gn = n0 + wn + j * 16 + l15;
    float bj = 0.f;
    if constexpr (MODE != MODE_W) bj = bias[gn];
#pragma unroll
    for (int i = 0; i < MI; ++i) {
#pragma unroll
      for (int r = 0; r < 4; ++r) {
        const int gm = m0 + wm + i * 16 + quad * 4 + r;
        if constexpr (MODE == MODE_W) {
          ((__bf16*)Cout)[(size_t)gm * N + gn] = (__bf16)accT[i][j][r];
        } else if constexpr (MODE == MODE_Q) {
          float v = acc[i][j][r] + bj;
          int idx = 0;
#pragma unroll
          for (int s = 128; s > 0; s >>= 1) {
            const int u = idx + s;
            if (cbs[u] <= v) idx = u;
          }
          float best = cbs[idx];
          if (idx < 255) {
            const float c1 = cbs[idx + 1];
            if (!(v - best <= c1 - v)) best = c1;
          }
          ((__bf16*)Cout)[(size_t)gm * N + gn] = (__bf16)best;
        } else {
          ((float*)Cout)[(size_t)gm * N + gn] = acc[i][j][r] + bj;
        }
      }
    }
  }
}

// ---- dispatch 2: fold1 (128) + fold2 (256) + ba (128) + w3T (512)
//      + x-cast (4096). smem union 16KB -> 6 blk/CU (launch_bounds cap). ----
__global__ __launch_bounds__(256, 6)
void foldA_kernel(const __bf16* __restrict__ w2b, const __bf16* __restrict__ w1T,
                  __bf16* __restrict__ WaT,
                  const __bf16* __restrict__ w5b, const __bf16* __restrict__ w4T,
                  __bf16* __restrict__ WtT,
                  const float* __restrict__ b1, const float* __restrict__ w2,
                  const float* __restrict__ b2, float* __restrict__ ba,
                  const float* __restrict__ w3, __bf16* __restrict__ w3T,
                  const float* __restrict__ x, __bf16* __restrict__ xb) {
  __shared__ __align__(16) char smem[16384];   // fold: As 8K + Bs 8K; tile 8.7K
  __bf16* As = (__bf16*)smem;
  __bf16* Bs = (__bf16*)(smem + 8192);
  int b = blockIdx.x;
  if (b < 128) {        // Wa = w2@w1: M=512, N=1024, K=4096, CH=512
    const int c = b & 7, i = b >> 3;            // XCD c gets by {2c,2c+1}
    gemm_body<MODE_W, 64>(As, Bs, nullptr, i >> 1, c * 2 + (i & 1), w2b, w1T, WaT,
                          nullptr, nullptr, DOUT, DIN, H1dim, 512);
  } else if (b < 384) { // Wt = w5@w4: M=512, N=2048, K=2048, CH=512
    b -= 128;
    const int c = b & 7, i = b >> 3;            // XCD c gets by {4c..4c+3}
    gemm_body<MODE_W, 64>(As, Bs, nullptr, i >> 2, c * 4 + (i & 3), w5b, w4T, WtT,
                          nullptr, nullptr, DOUT, H3dim, H4dim, 512);
  } else if (b < 512) { // ba
    bias_ba_body(b - 384, b1, w2, b2, ba);
  } else if (b < 1024) {// w3 [2048][512] -> w3T (consumed by foldB)
    b -= 512;
    transpose_body(w3, w3T, H3dim, DOUT, b & 15, b >> 4,
                   reinterpret_cast<float(*)[68]>(smem));
  } else {              // x fp32 -> bf16 (4096 blocks, coalesced)
    cast16_body(x, xb, b - 1024);
  }
}

// ---- dispatch 3: fold3 (64) + bc (128) + gemmQ (1024). smem 24KB+cbs ->
//      6 blk/CU. ----
__global__ __launch_bounds__(256, 6)
void foldB_kernel(const __bf16* __restrict__ WtT, const __bf16* __restrict__ w3T,
                  __bf16* __restrict__ WcT,
                  const float* __restrict__ b3, const float* __restrict__ b4,
                  const float* __restrict__ w5, const float* __restrict__ b5,
                  float* __restrict__ bc,
                  const __bf16* __restrict__ xb, const __bf16* __restrict__ WaT,
                  __bf16* __restrict__ q, const float* __restrict__ ba,
                  const float* __restrict__ cb) {
  __shared__ __align__(16) char smem[24576];   // gemmQ: As 16K + Bs 8K
  __shared__ float cbs[256];
  int b = blockIdx.x;
  if (b < 64) {         // Wc = Wt@w3: M=512, N=512, K=2048, CH=256
    __bf16* As = (__bf16*)smem;
    __bf16* Bs = (__bf16*)(smem + 8192);
    const int c = b & 7, i = b >> 3;            // XCD c gets by=c
    gemm_body<MODE_W, 64>(As, Bs, nullptr, i, c, WtT, w3T, WcT,
                          nullptr, nullptr, DOUT, DOUT, H3dim, 256);
  } else if (b < 192) { // bc (needs WtT)
    bias_bc_body(b - 64, b3, WtT, b4, w5, b5, bc);
  } else {              // h2 = xb@Wa + ba -> quantize -> q
    b -= 192;           // 192 % 8 == 0 -> XCD = b % 8 preserved
    __bf16* As = (__bf16*)smem;
    __bf16* Bs = (__bf16*)(smem + 16384);
    // XCD c: bx in [16c,16c+16); 8 consecutive blocks share one xb panel
    const int c = b & 7, i = b >> 3;
    gemm_body<MODE_Q, 128>(As, Bs, cbs, c * 16 + (i >> 3), i & 7, xb, WaT, q,
                           ba, cb, Bdim, DOUT, DIN, DIN);
  }
}

// ---- dispatch 4: out = q@Wc + bc (1024 blocks, 24KB -> 6 blk/CU) ----
__global__ __launch_bounds__(256, 6)
void gemmout_kernel(const __bf16* __restrict__ q, const __bf16* __restrict__ WcT,
                    float* __restrict__ out, const float* __restrict__ bc) {
  __shared__ __align__(16) char smem[24576];
  __bf16* As = (__bf16*)smem;
  __bf16* Bs = (__bf16*)(smem + 16384);
  const int b = blockIdx.x;
  const int c = b & 7, i = b >> 3;              // same remap as gemmQ
  gemm_body<MODE_OUT, 128>(As, Bs, nullptr, c * 16 + (i >> 3), i & 7,
                           q, WcT, out, bc, nullptr, Bdim, DOUT, DOUT, DOUT);
}

extern "C" void kernel_launch(void* const* d_in, const int* in_sizes, int n_in,
                              void* d_out, int out_size, void* d_ws, size_t ws_size,
                              hipStream_t stream) {
  const float* x  = (const float*)d_in[0];
  const float* cb = (const float*)d_in[1];
  const float* w1 = (const float*)d_in[2];   // [4096,1024]
  const float* b1 = (const float*)d_in[3];
  const float* w2 = (const float*)d_in[4];   // [512,4096]
  const float* b2 = (const float*)d_in[5];
  const float* w3 = (const float*)d_in[6];   // [2048,512]
  const float* b3 = (const float*)d_in[7];
  const float* w4 = (const float*)d_in[8];   // [2048,2048]
  const float* b4 = (const float*)d_in[9];
  const float* w5 = (const float*)d_in[10];  // [512,2048]
  const float* b5 = (const float*)d_in[11];
  float* out = (float*)d_out;

  char* ws = (char*)d_ws;
  size_t off = 0;
  auto alloc = [&](size_t bytes) -> void* {
    void* p = ws + off;
    off = (off + bytes + 255) & ~(size_t)255;
    return p;
  };
  __bf16* w1T = (__bf16*)alloc((size_t)DIN * H1dim * 2);     // 8 MB
  __bf16* w4T = (__bf16*)alloc((size_t)H3dim * H4dim * 2);   // 8 MB
  __bf16* w3T = (__bf16*)alloc((size_t)DOUT * H3dim * 2);    // 2 MB
  __bf16* w2b = (__bf16*)alloc((size_t)DOUT * H1dim * 2);    // 4 MB
  __bf16* w5b = (__bf16*)alloc((size_t)DOUT * H4dim * 2);    // 2 MB
  __bf16* WaT = (__bf16*)alloc((size_t)DOUT * DIN * 2);      // 1 MB
  __bf16* WtT = (__bf16*)alloc((size_t)DOUT * H3dim * 2);    // 2 MB
  __bf16* WcT = (__bf16*)alloc((size_t)DOUT * DOUT * 2);     // 0.5 MB
  __bf16* q   = (__bf16*)alloc((size_t)Bdim * DOUT * 2);     // 16 MB
  __bf16* xb  = (__bf16*)alloc((size_t)Bdim * DIN * 2);      // 32 MB
  float*  ba  = (float*)alloc(DOUT * 4);
  float*  bc  = (float*)alloc(DOUT * 4);

  // 1) w1/w4 transposes + w2/w5 casts
  prepw_kernel<<<4864, 256, 0, stream>>>(w1, w1T, w4, w4T, w2, w2b, w5, w5b);

  // 2) fold1 + fold2 + ba + w3 transpose + x-cast (overlap)
  foldA_kernel<<<5120, 256, 0, stream>>>(w2b, w1T, WaT, w5b, w4T, WtT,
                                         b1, w2, b2, ba, w3, w3T, x, xb);

  // 3) fold3 + bc + gemmQ
  foldB_kernel<<<1216, 256, 0, stream>>>(WtT, w3T, WcT, b3, b4, w5, b5, bc,
                                         xb, WaT, q, ba, cb);

  // 4) out = q@Wc + bc
  gemmout_kernel<<<1024, 256, 0, stream>>>(q, WcT, out, bc);
}

// Round 17
// 253.440 us; speedup vs baseline: 1.0363x; 1.0363x over previous
//
#include <hip/hip_runtime.h>

// ---------------------------------------------------------------------------
// network_49581102465567: 5-layer MLP, codebook quantize after layer 2.
// Folds: Wa = w2@w1 [512x1024], Wc = (w5@w4)@w3 [512x512].
// Round 22: FINAL — revert to R20 verbatim (verified best, 254.7us).
// R21's BK=32 falsified the occupancy lever in both directions (occ 24->42%
// yet foldA +8us; gemmQ neutral). All axes now probed both ways: tile shape,
// BK, occupancy, pipelining depth, split-K, fusion, XCD remap, coalescing.
// R20 is the local optimum of this structure:
//   prepw{w1T,w4T,w2b,w5b} -> foldA{fold1,fold2,ba,w3T,xcast}
//   -> foldB{fold3,bc,gemmQ} -> gemmout
// GEMM body: BMx64 tile, BK=64, DMA dbuf, counted-vmcnt + lgkmcnt(0) race
// fix, XOR chunk swizzle, XCD-locality remaps. absmax 0.005981445.
// ---------------------------------------------------------------------------

typedef __bf16 v8bf __attribute__((ext_vector_type(8)));
typedef float  v4f  __attribute__((ext_vector_type(4)));

#define Bdim   16384
#define DIN    1024
#define DOUT   512
#define H1dim  4096
#define H3dim  2048
#define H4dim  2048

#define GLOBAL_AS __attribute__((address_space(1)))
#define LDS_AS    __attribute__((address_space(3)))

__device__ __forceinline__ void load16_to_lds(const __bf16* g, __bf16* l) {
  __builtin_amdgcn_global_load_lds((const GLOBAL_AS unsigned int*)g,
                                   (LDS_AS unsigned int*)l, 16, 0, 0);
}

__device__ __forceinline__ unsigned pack2bf(float a, float b) {
  return (unsigned)__builtin_bit_cast(unsigned short, (__bf16)a) |
         ((unsigned)__builtin_bit_cast(unsigned short, (__bf16)b) << 16);
}

// ---- transposes (64 in-rows x 32 in-cols -> 128B writes) ----
__device__ __forceinline__ void transpose_body(const float* __restrict__ in,
                                               __bf16* __restrict__ out,
                                               int R, int C, int bx, int by,
                                               float (*tile)[68]) {
  const int c0 = bx * 32, r0 = by * 64;
  const int t = threadIdx.x, tr = t >> 5, tc = t & 31;
#pragma unroll
  for (int i = 0; i < 8; ++i)
    tile[tc][tr + i * 8] = in[(size_t)(r0 + tr + i * 8) * C + (c0 + tc)];
  __syncthreads();
  const int orow = t >> 3, oc = (t & 7) * 8;
  float4 a = *(const float4*)&tile[orow][oc];
  float4 b = *(const float4*)&tile[orow][oc + 4];
  int4 o;
  o.x = pack2bf(a.x, a.y); o.y = pack2bf(a.z, a.w);
  o.z = pack2bf(b.x, b.y); o.w = pack2bf(b.z, b.w);
  *(int4*)&out[(size_t)(c0 + orow) * R + (r0 + oc)] = o;
}

// ---- coalesced cast: block covers 4096 elems; chunk c, thread t ->
// elems [c*1024 + t*4, +4). Each load 1KB wave-contiguous. ----
__device__ __forceinline__ void cast16_body(const float* __restrict__ in,
                                            __bf16* __restrict__ out, int b) {
  const int t = threadIdx.x;
  const size_t base = (size_t)b * 4096;
#pragma unroll
  for (int c = 0; c < 4; ++c) {
    const size_t i = base + c * 1024 + t * 4;
    float4 v = *(const float4*)&in[i];
    uint2 o;
    o.x = pack2bf(v.x, v.y);
    o.y = pack2bf(v.z, v.w);
    *(uint2*)&out[i] = o;
  }
}

// ---- dispatch 1: w1/w4 transposes + w2/w5 casts (4864 blocks) ----
__global__ void prepw_kernel(const float* __restrict__ w1, __bf16* __restrict__ w1T,
                             const float* __restrict__ w4, __bf16* __restrict__ w4T,
                             const float* __restrict__ w2, __bf16* __restrict__ w2b,
                             const float* __restrict__ w5, __bf16* __restrict__ w5b) {
  __shared__ float tile[32][68];
  int b = blockIdx.x;
  if (b < 2048) {                 // w1 [4096][1024] -> w1T
    transpose_body(w1, w1T, H1dim, DIN, b & 31, b >> 5, tile);
  } else if (b < 4096) {          // w4 -> w4T
    b -= 2048;
    transpose_body(w4, w4T, H4dim, H3dim, b & 63, b >> 6, tile);
  } else if (b < 4608) {          // w2 -> bf16 (512 blocks)
    cast16_body(w2, w2b, b - 4096);
  } else {                        // w5 -> bf16 (256 blocks)
    cast16_body(w5, w5b, b - 4608);
  }
}

// ---- folded bias bodies (R11/R16) ----
__device__ __forceinline__ void bias_ba_body(int bb, const float* __restrict__ b1,
                                             const float* __restrict__ w2,
                                             const float* __restrict__ b2,
                                             float* __restrict__ ba) {
  const int wave = threadIdx.x >> 6, lane = threadIdx.x & 63;
  const int j = bb * 4 + wave;
  float s = 0.f;
  for (int k = lane; k < H1dim; k += 64) s += b1[k] * w2[(size_t)j * H1dim + k];
#pragma unroll
  for (int off = 32; off; off >>= 1) s += __shfl_xor(s, off, 64);
  if (lane == 0) ba[j] = s + b2[j];
}

__device__ __forceinline__ void bias_bc_body(int bb, const float* __restrict__ b3,
                                             const __bf16* __restrict__ WtT,
                                             const float* __restrict__ b4,
                                             const float* __restrict__ w5,
                                             const float* __restrict__ b5,
                                             float* __restrict__ bc) {
  const int wave = threadIdx.x >> 6, lane = threadIdx.x & 63;
  const int j = bb * 4 + wave;
  float s = 0.f;
  for (int k = lane; k < H4dim; k += 64)
    s += b3[k] * (float)WtT[(size_t)j * H4dim + k] + b4[k] * w5[(size_t)j * H4dim + k];
#pragma unroll
  for (int off = 32; off; off >>= 1) s += __shfl_xor(s, off, 64);
  if (lane == 0) bc[j] = s + b5[j];
}

// ---- unified bf16 GEMM body: BMx64 tile, BK=64, counted-vmcnt (R11) ----
enum { MODE_W = 0, MODE_Q = 1, MODE_OUT = 2 };

#define ASM_BAR() asm volatile("s_barrier" ::: "memory")

template <int MODE, int BM>
__device__ __forceinline__ void gemm_body(__bf16* As, __bf16* Bs, float* cbs,
                                          int bx, int by,
                                          const __bf16* __restrict__ A,
                                          const __bf16* __restrict__ Bt,
                                          void* __restrict__ Cout,
                                          const float* __restrict__ bias,
                                          const float* __restrict__ codebook,
                                          int M, int N, int K, int CH) {
  const int t = threadIdx.x;
  const int m0 = bx * BM, n0 = by * 64;
  if constexpr (MODE == MODE_Q) cbs[t] = codebook[t];

  const int lane = t & 63, wave = t >> 6;
  const int quad = lane >> 4, l15 = lane & 15;
  constexpr int MI = BM / 32;                 // A fragments per wave
  const int wm = (wave & 1) * (BM / 2), wn = (wave >> 1) * 32;

  // DMA staging: per gload 64 lanes x 16B = 8 rows x 64 bf16 (linear LDS).
  // Global source chunk XOR-swizzled by row&7; reads apply the same XOR.
  const int lrow = lane >> 3;
  const int gcol = ((lane & 7) ^ lrow) * 8;
  const __bf16* gA = A  + (size_t)(m0 + (BM / 4) * wave + lrow) * K + gcol;
  const __bf16* gB = Bt + (size_t)(n0 + 16 * wave + lrow) * K + gcol;
  const int swz = l15 & 7;

  v4f acc[MI][2], accT[MI][2];
#pragma unroll
  for (int i = 0; i < MI; ++i)
#pragma unroll
    for (int j = 0; j < 2; ++j) {
      acc[i][j] = (v4f){0.f, 0.f, 0.f, 0.f};
      if constexpr (MODE == MODE_W) accT[i][j] = (v4f){0.f, 0.f, 0.f, 0.f};
    }

  // stage = MI + 2 global_load_lds instructions per wave (LPS)
  auto stage = [&](int k0, int buf) {
    __bf16* lA = As + buf * (BM * 64) + (BM / 4) * wave * 64;
    __bf16* lB = Bs + buf * (64 * 64) + 16 * wave * 64;
#pragma unroll
    for (int p = 0; p < MI; ++p)
      load16_to_lds(gA + (size_t)(8 * p) * K + k0, lA + p * 512);
#pragma unroll
    for (int p = 0; p < 2; ++p)
      load16_to_lds(gB + (size_t)(8 * p) * K + k0, lB + p * 512);
  };

  const int nk = K >> 6;
  const int chsteps = CH >> 6;
  stage(0, 0);
  stage(64, 1);                    // 2*LPS loads in flight

  int cc = 0;
  for (int tk = 0; tk < nk; ++tk) {
    // drain ONLY stage(tk); stage(tk+1)'s LPS loads stay in flight
    if (tk + 1 < nk) {
      if constexpr (BM == 128) asm volatile("s_waitcnt vmcnt(6)" ::: "memory");
      else                     asm volatile("s_waitcnt vmcnt(4)" ::: "memory");
    } else {
      asm volatile("s_waitcnt vmcnt(0)" ::: "memory");
    }
    ASM_BAR();                     // all waves' stage(tk) visible

    const __bf16* cA = As + (tk & 1) * (BM * 64);
    const __bf16* cB = Bs + (tk & 1) * (64 * 64);
#pragma unroll
    for (int kk = 0; kk < 2; ++kk) {
      const int cch = ((kk * 4 + quad) ^ swz) * 8;
      v8bf af[MI], bv[2];
#pragma unroll
      for (int i = 0; i < MI; ++i)
        af[i] = *(const v8bf*)&cA[(wm + i * 16 + l15) * 64 + cch];
#pragma unroll
      for (int j = 0; j < 2; ++j)
        bv[j] = *(const v8bf*)&cB[(wn + j * 16 + l15) * 64 + cch];
#pragma unroll
      for (int i = 0; i < MI; ++i)
#pragma unroll
        for (int j = 0; j < 2; ++j)
          acc[i][j] = __builtin_amdgcn_mfma_f32_16x16x32_bf16(af[i], bv[j], acc[i][j], 0, 0, 0);
    }
    if constexpr (MODE == MODE_W) {
      if (++cc == chsteps) {        // chunk boundary: accT += chunk (left fold)
        cc = 0;
#pragma unroll
        for (int i = 0; i < MI; ++i)
#pragma unroll
          for (int j = 0; j < 2; ++j) {
            accT[i][j] += acc[i][j];
            acc[i][j] = (v4f){0.f, 0.f, 0.f, 0.f};
          }
      }
    }
    // Race fix (R10): fragment ds_reads must complete before any wave may
    // overwrite buf[tk&1] with stage(tk+2) DMA after the barrier.
    asm volatile("s_waitcnt lgkmcnt(0)" ::: "memory");
    ASM_BAR();                     // all waves done reading buf[tk&1]
    if (tk + 2 < nk) stage((tk + 2) << 6, tk & 1);   // refill freed buffer
  }

#pragma unroll
  for (int j = 0; j < 2; ++j) {
    const int gn = n0 + wn + j * 16 + l15;
    float bj = 0.f;
    if constexpr (MODE != MODE_W) bj = bias[gn];
#pragma unroll
    for (int i = 0; i < MI; ++i) {
#pragma unroll
      for (int r = 0; r < 4; ++r) {
        const int gm = m0 + wm + i * 16 + quad * 4 + r;
        if constexpr (MODE == MODE_W) {
          ((__bf16*)Cout)[(size_t)gm * N + gn] = (__bf16)accT[i][j][r];
        } else if constexpr (MODE == MODE_Q) {
          float v = acc[i][j][r] + bj;
          int idx = 0;
#pragma unroll
          for (int s = 128; s > 0; s >>= 1) {
            const int u = idx + s;
            if (cbs[u] <= v) idx = u;
          }
          float best = cbs[idx];
          if (idx < 255) {
            const float c1 = cbs[idx + 1];
            if (!(v - best <= c1 - v)) best = c1;
          }
          ((__bf16*)Cout)[(size_t)gm * N + gn] = (__bf16)best;
        } else {
          ((float*)Cout)[(size_t)gm * N + gn] = acc[i][j][r] + bj;
        }
      }
    }
  }
}

// ---- dispatch 2: fold1 (128) + fold2 (256) + ba (128) + w3T (512)
//      + x-cast (4096) — folds first, streams fill behind ----
__global__ __launch_bounds__(256, 3)
void foldA_kernel(const __bf16* __restrict__ w2b, const __bf16* __restrict__ w1T,
                  __bf16* __restrict__ WaT,
                  const __bf16* __restrict__ w5b, const __bf16* __restrict__ w4T,
                  __bf16* __restrict__ WtT,
                  const float* __restrict__ b1, const float* __restrict__ w2,
                  const float* __restrict__ b2, float* __restrict__ ba,
                  const float* __restrict__ w3, __bf16* __restrict__ w3T,
                  const float* __restrict__ x, __bf16* __restrict__ xb) {
  __shared__ __align__(16) __bf16 As[2 * 64 * 64];   // 16 KB
  __shared__ __align__(16) __bf16 Bs[2 * 64 * 64];   // 16 KB
  __shared__ float tile[32][68];                     // 8.5 KB (transpose)
  int b = blockIdx.x;
  if (b < 128) {        // Wa = w2@w1: M=512, N=1024, K=4096, CH=512
    const int c = b & 7, i = b >> 3;            // XCD c gets by {2c,2c+1}
    gemm_body<MODE_W, 64>(As, Bs, nullptr, i >> 1, c * 2 + (i & 1), w2b, w1T, WaT,
                          nullptr, nullptr, DOUT, DIN, H1dim, 512);
  } else if (b < 384) { // Wt = w5@w4: M=512, N=2048, K=2048, CH=512
    b -= 128;
    const int c = b & 7, i = b >> 3;            // XCD c gets by {4c..4c+3}
    gemm_body<MODE_W, 64>(As, Bs, nullptr, i >> 2, c * 4 + (i & 3), w5b, w4T, WtT,
                          nullptr, nullptr, DOUT, H3dim, H4dim, 512);
  } else if (b < 512) { // ba
    bias_ba_body(b - 384, b1, w2, b2, ba);
  } else if (b < 1024) {// w3 [2048][512] -> w3T (consumed by foldB)
    b -= 512;
    transpose_body(w3, w3T, H3dim, DOUT, b & 15, b >> 4, tile);
  } else {              // x fp32 -> bf16 (4096 blocks, coalesced)
    cast16_body(x, xb, b - 1024);
  }
}

// ---- dispatch 3: fold3 (64) + bc (128) + gemmQ (1024) ----
__global__ __launch_bounds__(256, 3)
void foldB_kernel(const __bf16* __restrict__ WtT, const __bf16* __restrict__ w3T,
                  __bf16* __restrict__ WcT,
                  const float* __restrict__ b3, const float* __restrict__ b4,
                  const float* __restrict__ w5, const float* __restrict__ b5,
                  float* __restrict__ bc,
                  const __bf16* __restrict__ xb, const __bf16* __restrict__ WaT,
                  __bf16* __restrict__ q, const float* __restrict__ ba,
                  const float* __restrict__ cb) {
  __shared__ __align__(16) __bf16 As[2 * 128 * 64];
  __shared__ __align__(16) __bf16 Bs[2 * 64 * 64];
  __shared__ float cbs[256];
  int b = blockIdx.x;
  if (b < 64) {         // Wc = Wt@w3: M=512, N=512, K=2048, CH=256
    const int c = b & 7, i = b >> 3;            // XCD c gets by=c
    gemm_body<MODE_W, 64>(As, Bs, nullptr, i, c, WtT, w3T, WcT,
                          nullptr, nullptr, DOUT, DOUT, H3dim, 256);
  } else if (b < 192) { // bc (needs WtT)
    bias_bc_body(b - 64, b3, WtT, b4, w5, b5, bc);
  } else {              // h2 = xb@Wa + ba -> quantize -> q
    b -= 192;           // 192 % 8 == 0 -> XCD = b % 8 preserved
    // XCD c: bx in [16c,16c+16); 8 consecutive blocks share one xb panel
    const int c = b & 7, i = b >> 3;
    gemm_body<MODE_Q, 128>(As, Bs, cbs, c * 16 + (i >> 3), i & 7, xb, WaT, q,
                           ba, cb, Bdim, DOUT, DIN, DIN);
  }
}

// ---- dispatch 4: out = q@Wc + bc ----
__global__ __launch_bounds__(256, 3)
void gemmout_kernel(const __bf16* __restrict__ q, const __bf16* __restrict__ WcT,
                    float* __restrict__ out, const float* __restrict__ bc) {
  __shared__ __align__(16) __bf16 As[2 * 128 * 64];
  __shared__ __align__(16) __bf16 Bs[2 * 64 * 64];
  const int b = blockIdx.x;
  const int c = b & 7, i = b >> 3;              // same remap as gemmQ
  gemm_body<MODE_OUT, 128>(As, Bs, nullptr, c * 16 + (i >> 3), i & 7,
                           q, WcT, out, bc, nullptr, Bdim, DOUT, DOUT, DOUT);
}

extern "C" void kernel_launch(void* const* d_in, const int* in_sizes, int n_in,
                              void* d_out, int out_size, void* d_ws, size_t ws_size,
                              hipStream_t stream) {
  const float* x  = (const float*)d_in[0];
  const float* cb = (const float*)d_in[1];
  const float* w1 = (const float*)d_in[2];   // [4096,1024]
  const float* b1 = (const float*)d_in[3];
  const float* w2 = (const float*)d_in[4];   // [512,4096]
  const float* b2 = (const float*)d_in[5];
  const float* w3 = (const float*)d_in[6];   // [2048,512]
  const float* b3 = (const float*)d_in[7];
  const float* w4 = (const float*)d_in[8];   // [2048,2048]
  const float* b4 = (const float*)d_in[9];
  const float* w5 = (const float*)d_in[10];  // [512,2048]
  const float* b5 = (const float*)d_in[11];
  float* out = (float*)d_out;

  char* ws = (char*)d_ws;
  size_t off = 0;
  auto alloc = [&](size_t bytes) -> void* {
    void* p = ws + off;
    off = (off + bytes + 255) & ~(size_t)255;
    return p;
  };
  __bf16* w1T = (__bf16*)alloc((size_t)DIN * H1dim * 2);     // 8 MB
  __bf16* w4T = (__bf16*)alloc((size_t)H3dim * H4dim * 2);   // 8 MB
  __bf16* w3T = (__bf16*)alloc((size_t)DOUT * H3dim * 2);    // 2 MB
  __bf16* w2b = (__bf16*)alloc((size_t)DOUT * H1dim * 2);    // 4 MB
  __bf16* w5b = (__bf16*)alloc((size_t)DOUT * H4dim * 2);    // 2 MB
  __bf16* WaT = (__bf16*)alloc((size_t)DOUT * DIN * 2);      // 1 MB
  __bf16* WtT = (__bf16*)alloc((size_t)DOUT * H3dim * 2);    // 2 MB
  __bf16* WcT = (__bf16*)alloc((size_t)DOUT * DOUT * 2);     // 0.5 MB
  __bf16* q   = (__bf16*)alloc((size_t)Bdim * DOUT * 2);     // 16 MB
  __bf16* xb  = (__bf16*)alloc((size_t)Bdim * DIN * 2);      // 32 MB
  float*  ba  = (float*)alloc(DOUT * 4);
  float*  bc  = (float*)alloc(DOUT * 4);

  // 1) w1/w4 transposes + w2/w5 casts
  prepw_kernel<<<4864, 256, 0, stream>>>(w1, w1T, w4, w4T, w2, w2b, w5, w5b);

  // 2) fold1 + fold2 + ba + w3 transpose + x-cast (overlap)
  foldA_kernel<<<5120, 256, 0, stream>>>(w2b, w1T, WaT, w5b, w4T, WtT,
                                         b1, w2, b2, ba, w3, w3T, x, xb);

  // 3) fold3 + bc + gemmQ
  foldB_kernel<<<1216, 256, 0, stream>>>(WtT, w3T, WcT, b3, b4, w5, b5, bc,
                                         xb, WaT, q, ba, cb);

  // 4) out = q@Wc + bc
  gemmout_kernel<<<1024, 256, 0, stream>>>(q, WcT, out, bc);
}